// Round 5
// baseline (276.170 us; speedup 1.0000x reference)
//
#include <hip/hip_runtime.h>
#include <hip/hip_bf16.h>

// Problem constants
#define BB   4
#define SS   2048
#define DIN  1024
#define DOUT 1024
#define NH   16
#define HDIM 64

typedef __hip_bfloat16 bf16;
typedef __attribute__((ext_vector_type(8))) short short8;   // bf16 MFMA A/B frag (4 VGPR)
typedef __attribute__((ext_vector_type(4))) float floatx4;  // MFMA C/D frag

#define AS1(p) ((const __attribute__((address_space(1))) void*)(p))
#define AS3(p) ((__attribute__((address_space(3))) void*)(p))

// ---------------------------------------------------------------- cast fp32 -> bf16
__global__ void cast_f32_bf16_kernel(const float* __restrict__ src, bf16* __restrict__ dst) {
    size_t i = ((size_t)blockIdx.x * 256 + threadIdx.x) * 8;
    float4 a = *(const float4*)(src + i);
    float4 b = *(const float4*)(src + i + 4);
    bf16 o[8] __attribute__((aligned(16)));
    o[0] = __float2bfloat16(a.x); o[1] = __float2bfloat16(a.y);
    o[2] = __float2bfloat16(a.z); o[3] = __float2bfloat16(a.w);
    o[4] = __float2bfloat16(b.x); o[5] = __float2bfloat16(b.y);
    o[6] = __float2bfloat16(b.z); o[7] = __float2bfloat16(b.w);
    *(short8*)(dst + i) = *(short8*)o;
}

// ------------------------------------------- build Wqkv^T (bf16, rows = output col n, cols = k)
__global__ void prep_wqkv_kernel(const float* __restrict__ Wq, const float* __restrict__ Wk,
                                 const float* __restrict__ Wv, bf16* __restrict__ wt) {
    __shared__ float tile[64][65];
    const int kt = blockIdx.x;          // 16 k-tiles
    const int nt = blockIdx.y;          // 48 n-tiles
    const int k0 = kt * 64, n0 = nt * 64;
    const float* W = (n0 < 1024) ? Wq : (n0 < 2048 ? Wk : Wv);
    const int col0 = n0 & 1023;
    const int tid = threadIdx.x;
    {
        const int kl = tid >> 2, nc = (tid & 3) * 16;
        const float* src = W + (size_t)(k0 + kl) * 1024 + col0 + nc;
        #pragma unroll
        for (int i = 0; i < 16; i += 4) {
            float4 v = *(const float4*)(src + i);
            tile[kl][nc + i + 0] = v.x; tile[kl][nc + i + 1] = v.y;
            tile[kl][nc + i + 2] = v.z; tile[kl][nc + i + 3] = v.w;
        }
    }
    __syncthreads();
    {
        const int nl = tid >> 2, kc = (tid & 3) * 16;
        bf16 o[16] __attribute__((aligned(16)));
        #pragma unroll
        for (int i = 0; i < 16; ++i) o[i] = __float2bfloat16(tile[kc + i][nl]);
        bf16* dst = wt + (size_t)(n0 + nl) * 1024 + k0 + kc;
        *(short8*)dst       = *(short8*)&o[0];
        *(short8*)(dst + 8) = *(short8*)&o[8];
    }
}

// ---------------------------------------------------------------- GEMM: C = A @ Bt^T (m97 structure)
template<int EPI>
__global__ __launch_bounds__(256) void gemm_bt_kernel(
    const bf16* __restrict__ A, const bf16* __restrict__ Bt,
    void* __restrict__ C, const float* __restrict__ bias, int K, int ldc) {
    __shared__ __align__(16) bf16 As[128][32];
    __shared__ __align__(16) bf16 Bs[128][32];
    const int tid  = threadIdx.x;
    const int wave = tid >> 6, lane = tid & 63;
    const int lm   = lane & 15, quad = lane >> 4;
    const int wm   = (wave >> 1) * 64, wn = (wave & 1) * 64;
    const size_t rowA0 = (size_t)blockIdx.x * 128;
    const size_t rowB0 = (size_t)blockIdx.y * 128;
    const int srow = wave * 16 + (lane >> 2);
    const int skc  = (lane & 3) * 8;

    floatx4 acc[4][4] = {};

    for (int k0 = 0; k0 < K; k0 += 32) {
        __syncthreads();
        #pragma unroll
        for (int r = 0; r < 2; ++r) {
            const bf16* gA = A  + (rowA0 + r * 64 + srow) * (size_t)K + k0 + skc;
            __builtin_amdgcn_global_load_lds(AS1(gA), AS3(&As[r * 64 + wave * 16][0]), 16, 0, 0);
            const bf16* gB = Bt + (rowB0 + r * 64 + srow) * (size_t)K + k0 + skc;
            __builtin_amdgcn_global_load_lds(AS1(gB), AS3(&Bs[r * 64 + wave * 16][0]), 16, 0, 0);
        }
        __syncthreads();
        short8 a[4], b[4];
        #pragma unroll
        for (int i = 0; i < 4; ++i) a[i] = *(const short8*)&As[wm + i * 16 + lm][quad * 8];
        #pragma unroll
        for (int j = 0; j < 4; ++j) b[j] = *(const short8*)&Bs[wn + j * 16 + lm][quad * 8];
        #pragma unroll
        for (int i = 0; i < 4; ++i)
            #pragma unroll
            for (int j = 0; j < 4; ++j)
                acc[i][j] = __builtin_amdgcn_mfma_f32_16x16x32_bf16(a[i], b[j], acc[i][j], 0, 0, 0);
    }

    #pragma unroll
    for (int i = 0; i < 4; ++i) {
        size_t row = rowA0 + wm + i * 16 + quad * 4;
        #pragma unroll
        for (int j = 0; j < 4; ++j) {
            size_t col = rowB0 + wn + j * 16 + lm;
            float bv = (EPI == 1) ? bias[col] : 0.0f;
            #pragma unroll
            for (int r = 0; r < 4; ++r) {
                if (EPI == 0)
                    ((bf16*)C)[(row + r) * ldc + col] = __float2bfloat16(acc[i][j][r]);
                else
                    ((float*)C)[(row + r) * ldc + col] = acc[i][j][r] + bv;
            }
        }
    }
}

// ---------------------------------------------------------------- V -> Vt[b,h,hd,s]
__global__ void transpose_v_kernel(const bf16* __restrict__ qkv, bf16* __restrict__ vt) {
    __shared__ __align__(16) bf16 tile[64][72];
    const int st = blockIdx.x;
    const int bh = blockIdx.y;
    const int b = bh >> 4, h = bh & 15;
    const int s0 = st * 64;
    const int tid = threadIdx.x;
    {
        const int sl = tid >> 2, hc = (tid & 3) * 16;
        const bf16* src = qkv + ((size_t)(b * SS + s0 + sl)) * 3072 + 2048 + h * 64 + hc;
        *(short8*)&tile[sl][hc]     = *(const short8*)src;
        *(short8*)&tile[sl][hc + 8] = *(const short8*)(src + 8);
    }
    __syncthreads();
    {
        const int hl = tid >> 2, sc = (tid & 3) * 16;
        bf16 o[16] __attribute__((aligned(16)));
        #pragma unroll
        for (int i = 0; i < 16; ++i) o[i] = tile[sc + i][hl];
        bf16* dst = vt + ((size_t)(bh * 64 + hl)) * SS + s0 + sc;
        *(short8*)dst       = *(short8*)&o[0];
        *(short8*)(dst + 8) = *(short8*)&o[8];
    }
}

// ---------------------------------------------------------------- causal flash attention v5
// Block = 64 q rows (4 waves x 16). Grid = 1024 = 64 bh x 16 qt-pairs (qt <-> 31-qt,
// uniform 33 kt-iters). 4 blocks/CU (round-4 was grid-capped at 2 -> 18% occupancy).
// Cooperative K/V LDS staging via global_load_lds + XOR chunk swizzle (0 conflicts, r4).
// XCD swizzle: 8 bh per XCD -> 4 MB K/V working set = per-XCD L2 (FETCH 27 MB, r4).
// S computed transposed (S^T = K.Q^T) -> P packs 4 consecutive keys per b64 LDS write.
#define PSTR 68
__global__ __launch_bounds__(256, 4) void flash_attn_kernel(
    const bf16* __restrict__ qkv, const bf16* __restrict__ vt, bf16* __restrict__ ctx) {
    __shared__ __align__(16) bf16 Ks[64 * 64];          // [token row][d chunk-swizzled]
    __shared__ __align__(16) bf16 Vs[64 * 64];          // [hd row][key chunk-swizzled]
    __shared__ __align__(16) bf16 Pl[4][16 * PSTR + 8]; // per-wave P (C->A layout)
    const int tid  = threadIdx.x;
    const int wave = tid >> 6, lane = tid & 63;
    const int lm   = lane & 15, quad = lane >> 4;

    // XCD swizzle: id&7 = XCD; the 16 blocks of one (b,h) share that XCD's L2
    const int id  = blockIdx.x;          // 0..1023
    const int w   = id >> 3;             // 0..127
    const int bh  = (id & 7) * 8 + (w & 7);
    const int pr  = w >> 3;              // 0..15 -> q-tiles {pr, 31-pr}
    const int b = bh >> 4, h = bh & 15;

    // staging decode: lane -> (row-in-8-group, chunk); source chunk XOR-swizzled
    const int lane8r = lane >> 3;        // == row & 7
    const int schunk = (lane & 7) ^ lane8r;

    bf16* Pw = &Pl[wave][0];

    #pragma unroll 1
    for (int ph = 0; ph < 2; ++ph) {
        const int qt = ph ? (31 - pr) : pr;      // 64-row q-tile index
        const int q0 = qt * 64 + wave * 16;      // wave's first q row
        const int nkt = qt + 1;

        // Q B-fragment: n=lm -> q row, k=quad*8+j -> d
        const bf16* qp = qkv + ((size_t)(b * SS + q0 + lm)) * 3072 + h * 64 + quad * 8;
        const short8 bq0 = *(const short8*)qp;
        const short8 bq1 = *(const short8*)(qp + 32);

        floatx4 o[4] = {};
        float lsum = 0.0f;

        #pragma unroll 1
        for (int kt = 0; kt < nkt; ++kt) {
            __syncthreads();   // readers of previous tile done
            #pragma unroll
            for (int c = 0; c < 2; ++c) {
                const int row = c * 32 + wave * 8 + lane8r;
                const bf16* gk = qkv + ((size_t)(b * SS + kt * 64 + row)) * 3072 + 1024 + h * 64 + schunk * 8;
                __builtin_amdgcn_global_load_lds(AS1(gk), AS3(Ks + (c * 256 + wave * 64) * 8), 16, 0, 0);
                const bf16* gv = vt + ((size_t)((b * NH + h) * 64 + row)) * SS + kt * 64 + schunk * 8;
                __builtin_amdgcn_global_load_lds(AS1(gv), AS3(Vs + (c * 256 + wave * 64) * 8), 16, 0, 0);
            }
            __syncthreads();   // drains vmcnt -> tiles visible

            // K A-frags + V B-frags from LDS (XOR-swizzled chunks; 0 conflicts measured)
            const int sw = lm & 7;
            short8 ka[4][2], va[4][2];
            #pragma unroll
            for (int nt = 0; nt < 4; ++nt) {
                const int r0 = (nt * 16 + lm) * 64;
                ka[nt][0] = *(const short8*)(Ks + r0 + ((quad ^ sw) * 8));
                ka[nt][1] = *(const short8*)(Ks + r0 + (((4 + quad) ^ sw) * 8));
                va[nt][0] = *(const short8*)(Vs + r0 + ((quad ^ sw) * 8));
                va[nt][1] = *(const short8*)(Vs + r0 + (((4 + quad) ^ sw) * 8));
            }

            // S^T tile: row=key nt*16+quad*4+r, col=q lm
            floatx4 sc[4];
            #pragma unroll
            for (int nt = 0; nt < 4; ++nt) {
                floatx4 z = {};
                z = __builtin_amdgcn_mfma_f32_16x16x32_bf16(ka[nt][0], bq0, z, 0, 0, 0);
                z = __builtin_amdgcn_mfma_f32_16x16x32_bf16(ka[nt][1], bq1, z, 0, 0, 0);
                sc[nt] = z;
            }
            // causal mask on the diagonal tile (wave-uniform branch)
            if (kt == qt) {
                #pragma unroll
                for (int nt = 0; nt < 4; ++nt)
                    #pragma unroll
                    for (int r = 0; r < 4; ++r)
                        if (nt * 16 + quad * 4 + r > wave * 16 + lm) sc[nt][r] = -1e30f;
            }
            // p = exp(s/8) = 2^(s*0.18033688); per-lane row sums; pack 4 keys -> b64
            #pragma unroll
            for (int nt = 0; nt < 4; ++nt) {
                bf16 pk[4] __attribute__((aligned(8)));
                #pragma unroll
                for (int r = 0; r < 4; ++r) {
                    float pv = __builtin_amdgcn_exp2f(sc[nt][r] * 0.18033688f);
                    lsum += pv;
                    pk[r] = __float2bfloat16(pv);
                }
                *(uint64_t*)&Pw[lm * PSTR + nt * 16 + quad * 4] = *(uint64_t*)pk;
            }
            // P A-frags (in-order DS pipe) + PV accumulate (B = Vs rows)
            const short8 ap0 = *(const short8*)&Pw[lm * PSTR + quad * 8];
            const short8 ap1 = *(const short8*)&Pw[lm * PSTR + 32 + quad * 8];
            #pragma unroll
            for (int t = 0; t < 4; ++t) {
                o[t] = __builtin_amdgcn_mfma_f32_16x16x32_bf16(ap0, va[t][0], o[t], 0, 0, 0);
                o[t] = __builtin_amdgcn_mfma_f32_16x16x32_bf16(ap1, va[t][1], o[t], 0, 0, 0);
            }
        }

        // row sums: lanes {lm, lm+16, lm+32, lm+48} hold partials for q-row q0+lm
        float rsum = lsum;
        rsum += __shfl_xor(rsum, 16);
        rsum += __shfl_xor(rsum, 32);
        float rl[4];
        #pragma unroll
        for (int r = 0; r < 4; ++r) rl[r] = 1.0f / __shfl(rsum, quad * 4 + r);
        // normalize + store ctx[b, s, h*64+hd]
        #pragma unroll
        for (int t = 0; t < 4; ++t)
            #pragma unroll
            for (int r = 0; r < 4; ++r) {
                size_t row = (size_t)b * SS + q0 + quad * 4 + r;
                ctx[row * 1024 + h * 64 + t * 16 + lm] = __float2bfloat16(o[t][r] * rl[r]);
            }
    }
}

// ---------------------------------------------------------------- launch
extern "C" void kernel_launch(void* const* d_in, const int* in_sizes, int n_in,
                              void* d_out, int out_size, void* d_ws, size_t ws_size,
                              hipStream_t stream) {
    const float* x  = (const float*)d_in[0];
    const float* Wq = (const float*)d_in[1];
    const float* Wk = (const float*)d_in[2];
    const float* Wv = (const float*)d_in[3];
    const float* Wo = (const float*)d_in[4];
    const float* bo = (const float*)d_in[5];

    char* ws = (char*)d_ws;
    bf16* xb  = (bf16*)ws;  ws += (size_t)8192 * 1024 * 2;   // 16 MB (reused as ctx)
    bf16* wt  = (bf16*)ws;  ws += (size_t)3072 * 1024 * 2;   //  6 MB
    bf16* wob = (bf16*)ws;  ws += (size_t)1024 * 1024 * 2;   //  2 MB
    bf16* qkv = (bf16*)ws;  ws += (size_t)8192 * 3072 * 2;   // 48 MB
    bf16* vtb = (bf16*)ws;  ws += (size_t)BB * NH * HDIM * SS * 2;  // 16 MB
    bf16* ctx = xb;  // xb dead after gemm_qkv -> alias

    cast_f32_bf16_kernel<<<4096, 256, 0, stream>>>(x, xb);
    prep_wqkv_kernel<<<dim3(16, 48), 256, 0, stream>>>(Wq, Wk, Wv, wt);
    cast_f32_bf16_kernel<<<512, 256, 0, stream>>>(Wo, wob);
    gemm_bt_kernel<0><<<dim3(64, 24), 256, 0, stream>>>(xb, wt, (void*)qkv, nullptr, 1024, 3072);
    transpose_v_kernel<<<dim3(32, 64), 256, 0, stream>>>(qkv, vtb);
    flash_attn_kernel<<<1024, 256, 0, stream>>>(qkv, vtb, ctx);
    gemm_bt_kernel<1><<<dim3(64, 8), 256, 0, stream>>>(ctx, wob, d_out, bo, 1024, 1024);
}

// Round 6
// 273.065 us; speedup vs baseline: 1.0114x; 1.0114x over previous
//
#include <hip/hip_runtime.h>
#include <hip/hip_bf16.h>

// Problem constants
#define BB   4
#define SS   2048
#define DIN  1024
#define DOUT 1024
#define NH   16
#define HDIM 64

typedef __hip_bfloat16 bf16;
typedef __attribute__((ext_vector_type(8))) short short8;   // bf16 MFMA A/B frag (4 VGPR)
typedef __attribute__((ext_vector_type(4))) float floatx4;  // MFMA C/D frag

#define AS1(p) ((const __attribute__((address_space(1))) void*)(p))
#define AS3(p) ((__attribute__((address_space(3))) void*)(p))

// ---------------------------------------------------------------- cast fp32 -> bf16
__global__ void cast_f32_bf16_kernel(const float* __restrict__ src, bf16* __restrict__ dst) {
    size_t i = ((size_t)blockIdx.x * 256 + threadIdx.x) * 8;
    float4 a = *(const float4*)(src + i);
    float4 b = *(const float4*)(src + i + 4);
    bf16 o[8] __attribute__((aligned(16)));
    o[0] = __float2bfloat16(a.x); o[1] = __float2bfloat16(a.y);
    o[2] = __float2bfloat16(a.z); o[3] = __float2bfloat16(a.w);
    o[4] = __float2bfloat16(b.x); o[5] = __float2bfloat16(b.y);
    o[6] = __float2bfloat16(b.z); o[7] = __float2bfloat16(b.w);
    *(short8*)(dst + i) = *(short8*)o;
}

// ------------------------------------------- build Wqkv^T (bf16, rows = output col n, cols = k)
__global__ void prep_wqkv_kernel(const float* __restrict__ Wq, const float* __restrict__ Wk,
                                 const float* __restrict__ Wv, bf16* __restrict__ wt) {
    __shared__ float tile[64][65];
    const int kt = blockIdx.x;          // 16 k-tiles
    const int nt = blockIdx.y;          // 48 n-tiles
    const int k0 = kt * 64, n0 = nt * 64;
    const float* W = (n0 < 1024) ? Wq : (n0 < 2048 ? Wk : Wv);
    const int col0 = n0 & 1023;
    const int tid = threadIdx.x;
    {
        const int kl = tid >> 2, nc = (tid & 3) * 16;
        const float* src = W + (size_t)(k0 + kl) * 1024 + col0 + nc;
        #pragma unroll
        for (int i = 0; i < 16; i += 4) {
            float4 v = *(const float4*)(src + i);
            tile[kl][nc + i + 0] = v.x; tile[kl][nc + i + 1] = v.y;
            tile[kl][nc + i + 2] = v.z; tile[kl][nc + i + 3] = v.w;
        }
    }
    __syncthreads();
    {
        const int nl = tid >> 2, kc = (tid & 3) * 16;
        bf16 o[16] __attribute__((aligned(16)));
        #pragma unroll
        for (int i = 0; i < 16; ++i) o[i] = __float2bfloat16(tile[kc + i][nl]);
        bf16* dst = wt + (size_t)(n0 + nl) * 1024 + k0 + kc;
        *(short8*)dst       = *(short8*)&o[0];
        *(short8*)(dst + 8) = *(short8*)&o[8];
    }
}

// ---------------------------------------------------------------- GEMM: C = A @ Bt^T (m97 structure)
template<int EPI>
__global__ __launch_bounds__(256) void gemm_bt_kernel(
    const bf16* __restrict__ A, const bf16* __restrict__ Bt,
    void* __restrict__ C, const float* __restrict__ bias, int K, int ldc) {
    __shared__ __align__(16) bf16 As[128][32];
    __shared__ __align__(16) bf16 Bs[128][32];
    const int tid  = threadIdx.x;
    const int wave = tid >> 6, lane = tid & 63;
    const int lm   = lane & 15, quad = lane >> 4;
    const int wm   = (wave >> 1) * 64, wn = (wave & 1) * 64;
    const size_t rowA0 = (size_t)blockIdx.x * 128;
    const size_t rowB0 = (size_t)blockIdx.y * 128;
    const int srow = wave * 16 + (lane >> 2);
    const int skc  = (lane & 3) * 8;

    floatx4 acc[4][4] = {};

    for (int k0 = 0; k0 < K; k0 += 32) {
        __syncthreads();
        #pragma unroll
        for (int r = 0; r < 2; ++r) {
            const bf16* gA = A  + (rowA0 + r * 64 + srow) * (size_t)K + k0 + skc;
            __builtin_amdgcn_global_load_lds(AS1(gA), AS3(&As[r * 64 + wave * 16][0]), 16, 0, 0);
            const bf16* gB = Bt + (rowB0 + r * 64 + srow) * (size_t)K + k0 + skc;
            __builtin_amdgcn_global_load_lds(AS1(gB), AS3(&Bs[r * 64 + wave * 16][0]), 16, 0, 0);
        }
        __syncthreads();
        short8 a[4], b[4];
        #pragma unroll
        for (int i = 0; i < 4; ++i) a[i] = *(const short8*)&As[wm + i * 16 + lm][quad * 8];
        #pragma unroll
        for (int j = 0; j < 4; ++j) b[j] = *(const short8*)&Bs[wn + j * 16 + lm][quad * 8];
        #pragma unroll
        for (int i = 0; i < 4; ++i)
            #pragma unroll
            for (int j = 0; j < 4; ++j)
                acc[i][j] = __builtin_amdgcn_mfma_f32_16x16x32_bf16(a[i], b[j], acc[i][j], 0, 0, 0);
    }

    #pragma unroll
    for (int i = 0; i < 4; ++i) {
        size_t row = rowA0 + wm + i * 16 + quad * 4;
        #pragma unroll
        for (int j = 0; j < 4; ++j) {
            size_t col = rowB0 + wn + j * 16 + lm;
            float bv = (EPI == 1) ? bias[col] : 0.0f;
            #pragma unroll
            for (int r = 0; r < 4; ++r) {
                if (EPI == 0)
                    ((bf16*)C)[(row + r) * ldc + col] = __float2bfloat16(acc[i][j][r]);
                else
                    ((float*)C)[(row + r) * ldc + col] = acc[i][j][r] + bv;
            }
        }
    }
}

// ---------------------------------------------------------------- V -> Vt[b,h,hd,s]
__global__ void transpose_v_kernel(const bf16* __restrict__ qkv, bf16* __restrict__ vt) {
    __shared__ __align__(16) bf16 tile[64][72];
    const int st = blockIdx.x;
    const int bh = blockIdx.y;
    const int b = bh >> 4, h = bh & 15;
    const int s0 = st * 64;
    const int tid = threadIdx.x;
    {
        const int sl = tid >> 2, hc = (tid & 3) * 16;
        const bf16* src = qkv + ((size_t)(b * SS + s0 + sl)) * 3072 + 2048 + h * 64 + hc;
        *(short8*)&tile[sl][hc]     = *(const short8*)src;
        *(short8*)&tile[sl][hc + 8] = *(const short8*)(src + 8);
    }
    __syncthreads();
    {
        const int hl = tid >> 2, sc = (tid & 3) * 16;
        bf16 o[16] __attribute__((aligned(16)));
        #pragma unroll
        for (int i = 0; i < 16; ++i) o[i] = tile[sc + i][hl];
        bf16* dst = vt + ((size_t)(bh * 64 + hl)) * SS + s0 + sc;
        *(short8*)dst       = *(short8*)&o[0];
        *(short8*)(dst + 8) = *(short8*)&o[8];
    }
}

// ---------------------------------------------------------------- causal flash attention v6
// r4 shape (128 q rows/block, 4 waves x 32, 2 q-groups amortize K/V LDS reads; grid 512,
// XCD swizzle -> 4 MB working set per XCD; XOR chunk swizzle -> 0 bank conflicts) PLUS
// single-barrier double-buffered staging: loads for tile kt+1 are issued right after the
// barrier that confirms tile kt arrived, so they fly during ALL of kt's compute. The
// compiler's vmcnt(0)-before-s_barrier then drains an already-complete DMA (was the ~80%
// per-iter stall in r4/r5's 2-barrier structure).
#define PSTR 68
__global__ __launch_bounds__(256, 2) void flash_attn_kernel(
    const bf16* __restrict__ qkv, const bf16* __restrict__ vt, bf16* __restrict__ ctx) {
    __shared__ __align__(16) bf16 Ks[2][64 * 64];       // double-buffered K tile
    __shared__ __align__(16) bf16 Vs[2][64 * 64];       // double-buffered V tile
    __shared__ __align__(16) bf16 Pl[4][32 * PSTR + 8]; // per-wave P (C->A layout)
    const int tid  = threadIdx.x;
    const int wave = tid >> 6, lane = tid & 63;
    const int lm   = lane & 15, quad = lane >> 4;

    // XCD swizzle: id&7 = XCD; blocks of same (b,h) share an XCD's L2
    const int id  = blockIdx.x;          // 0..511
    const int j   = id >> 3;             // 0..63
    const int bh  = (id & 7) * 8 + (j & 7);
    const int p0  = j >> 3;              // 0..7 -> q-tiles {p0, 15-p0}
    const int b = bh >> 4, h = bh & 15;

    // staging decode: lane -> (row-in-8-group, chunk); source chunk XOR-swizzled
    const int lane8r = lane >> 3;        // == row & 7
    const int schunk = (lane & 7) ^ lane8r;

    const bf16* kg = qkv + (size_t)b * SS * 3072 + 1024 + h * 64 + schunk * 8;
    const bf16* vg = vt + (size_t)(b * NH + h) * 64 * SS + schunk * 8;

    bf16* Pw = &Pl[wave][0];

    #pragma unroll 1
    for (int ph = 0; ph < 2; ++ph) {
        const int p = ph ? (15 - p0) : p0;       // 128-row q-tile index
        const int qb = p * 128 + wave * 32;      // wave's first q row
        const int nkt = 2 * p + 2;

        // Q B-fragments for 2 groups of 16 q-rows: n=lm -> q row, k=quad*8+j -> d
        short8 bq[2][2];
        #pragma unroll
        for (int g = 0; g < 2; ++g) {
            const bf16* qp = qkv + ((size_t)(b * SS + qb + g * 16 + lm)) * 3072 + h * 64 + quad * 8;
            bq[g][0] = *(const short8*)qp;
            bq[g][1] = *(const short8*)(qp + 32);
        }

        floatx4 o[2][4] = {};
        float lsum[2] = {0.f, 0.f};

        // prime the pipeline: tile 0 -> buffer 0
        if (ph) __syncthreads();   // phase-0 readers of the last buffer done
        #pragma unroll
        for (int c = 0; c < 2; ++c) {
            const int row = c * 32 + wave * 8 + lane8r;
            __builtin_amdgcn_global_load_lds(AS1(kg + (size_t)row * 3072), AS3(&Ks[0][(c * 256 + wave * 64) * 8]), 16, 0, 0);
            __builtin_amdgcn_global_load_lds(AS1(vg + (size_t)row * SS), AS3(&Vs[0][(c * 256 + wave * 64) * 8]), 16, 0, 0);
        }

        #pragma unroll 1
        for (int kt = 0; kt < nkt; ++kt) {
            const int cur = kt & 1;
            __syncthreads();   // tile kt arrived (vmcnt drain); buf^1 readers done
            // stage tile kt+1 into the other buffer -> in flight during kt's compute
            if (kt + 1 < nkt) {
                #pragma unroll
                for (int c = 0; c < 2; ++c) {
                    const int row = c * 32 + wave * 8 + lane8r;
                    __builtin_amdgcn_global_load_lds(AS1(kg + (size_t)((kt + 1) * 64 + row) * 3072),
                                                     AS3(&Ks[cur ^ 1][(c * 256 + wave * 64) * 8]), 16, 0, 0);
                    __builtin_amdgcn_global_load_lds(AS1(vg + (size_t)row * SS + (kt + 1) * 64),
                                                     AS3(&Vs[cur ^ 1][(c * 256 + wave * 64) * 8]), 16, 0, 0);
                }
            }

            // K A-frags + V B-frags from LDS (XOR-swizzled chunks; 0 conflicts measured)
            const int sw = lm & 7;
            const bf16* Ksb = &Ks[cur][0];
            const bf16* Vsb = &Vs[cur][0];
            short8 ka[4][2], va[4][2];
            #pragma unroll
            for (int nt = 0; nt < 4; ++nt) {
                const int r0 = (nt * 16 + lm) * 64;
                ka[nt][0] = *(const short8*)(Ksb + r0 + ((quad ^ sw) * 8));
                ka[nt][1] = *(const short8*)(Ksb + r0 + (((4 + quad) ^ sw) * 8));
                va[nt][0] = *(const short8*)(Vsb + r0 + ((quad ^ sw) * 8));
                va[nt][1] = *(const short8*)(Vsb + r0 + (((4 + quad) ^ sw) * 8));
            }

            #pragma unroll
            for (int g = 0; g < 2; ++g) {
                // S^T tile: row=key nt*16+quad*4+r, col=q g*16+lm
                floatx4 sc[4];
                #pragma unroll
                for (int nt = 0; nt < 4; ++nt) {
                    floatx4 z = {};
                    z = __builtin_amdgcn_mfma_f32_16x16x32_bf16(ka[nt][0], bq[g][0], z, 0, 0, 0);
                    z = __builtin_amdgcn_mfma_f32_16x16x32_bf16(ka[nt][1], bq[g][1], z, 0, 0, 0);
                    sc[nt] = z;
                }
                // causal mask (only near the diagonal; wave-uniform guard)
                if (kt * 64 + 63 > qb + g * 16) {
                    const int qrow = qb + g * 16 + lm;
                    #pragma unroll
                    for (int nt = 0; nt < 4; ++nt)
                        #pragma unroll
                        for (int r = 0; r < 4; ++r)
                            if (kt * 64 + nt * 16 + quad * 4 + r > qrow) sc[nt][r] = -1e30f;
                }
                // p = exp(s/8) = 2^(s*0.18033688); per-lane row sums; pack 4 keys -> b64
                #pragma unroll
                for (int nt = 0; nt < 4; ++nt) {
                    bf16 pk[4] __attribute__((aligned(8)));
                    #pragma unroll
                    for (int r = 0; r < 4; ++r) {
                        float pv = __builtin_amdgcn_exp2f(sc[nt][r] * 0.18033688f);
                        lsum[g] += pv;
                        pk[r] = __float2bfloat16(pv);
                    }
                    *(uint64_t*)&Pw[(g * 16 + lm) * PSTR + nt * 16 + quad * 4] = *(uint64_t*)pk;
                }
            }
            // P A-frags (in-order DS pipe) + PV accumulate
            #pragma unroll
            for (int g = 0; g < 2; ++g) {
                const short8 ap0 = *(const short8*)&Pw[(g * 16 + lm) * PSTR + quad * 8];
                const short8 ap1 = *(const short8*)&Pw[(g * 16 + lm) * PSTR + 32 + quad * 8];
                #pragma unroll
                for (int t = 0; t < 4; ++t) {
                    o[g][t] = __builtin_amdgcn_mfma_f32_16x16x32_bf16(ap0, va[t][0], o[g][t], 0, 0, 0);
                    o[g][t] = __builtin_amdgcn_mfma_f32_16x16x32_bf16(ap1, va[t][1], o[g][t], 0, 0, 0);
                }
            }
        }

        // row sums: lanes {lm, lm+16, lm+32, lm+48} hold partials for q-row qb+g*16+lm
        #pragma unroll
        for (int g = 0; g < 2; ++g) {
            float rsum = lsum[g];
            rsum += __shfl_xor(rsum, 16);
            rsum += __shfl_xor(rsum, 32);
            float rl[4];
            #pragma unroll
            for (int r = 0; r < 4; ++r) rl[r] = 1.0f / __shfl(rsum, quad * 4 + r);
            #pragma unroll
            for (int t = 0; t < 4; ++t)
                #pragma unroll
                for (int r = 0; r < 4; ++r) {
                    size_t row = (size_t)b * SS + qb + g * 16 + quad * 4 + r;
                    ctx[row * 1024 + h * 64 + t * 16 + lm] = __float2bfloat16(o[g][t][r] * rl[r]);
                }
        }
    }
}

// ---------------------------------------------------------------- launch
extern "C" void kernel_launch(void* const* d_in, const int* in_sizes, int n_in,
                              void* d_out, int out_size, void* d_ws, size_t ws_size,
                              hipStream_t stream) {
    const float* x  = (const float*)d_in[0];
    const float* Wq = (const float*)d_in[1];
    const float* Wk = (const float*)d_in[2];
    const float* Wv = (const float*)d_in[3];
    const float* Wo = (const float*)d_in[4];
    const float* bo = (const float*)d_in[5];

    char* ws = (char*)d_ws;
    bf16* xb  = (bf16*)ws;  ws += (size_t)8192 * 1024 * 2;   // 16 MB (reused as ctx)
    bf16* wt  = (bf16*)ws;  ws += (size_t)3072 * 1024 * 2;   //  6 MB
    bf16* wob = (bf16*)ws;  ws += (size_t)1024 * 1024 * 2;   //  2 MB
    bf16* qkv = (bf16*)ws;  ws += (size_t)8192 * 3072 * 2;   // 48 MB
    bf16* vtb = (bf16*)ws;  ws += (size_t)BB * NH * HDIM * SS * 2;  // 16 MB
    bf16* ctx = xb;  // xb dead after gemm_qkv -> alias

    cast_f32_bf16_kernel<<<4096, 256, 0, stream>>>(x, xb);
    prep_wqkv_kernel<<<dim3(16, 48), 256, 0, stream>>>(Wq, Wk, Wv, wt);
    cast_f32_bf16_kernel<<<512, 256, 0, stream>>>(Wo, wob);
    gemm_bt_kernel<0><<<dim3(64, 24), 256, 0, stream>>>(xb, wt, (void*)qkv, nullptr, 1024, 3072);
    transpose_v_kernel<<<dim3(32, 64), 256, 0, stream>>>(qkv, vtb);
    flash_attn_kernel<<<512, 256, 0, stream>>>(qkv, vtb, ctx);
    gemm_bt_kernel<1><<<dim3(64, 8), 256, 0, stream>>>(ctx, wob, d_out, bo, 1024, 1024);
}